// Round 10
// baseline (384.825 us; speedup 1.0000x reference)
//
#include <hip/hip_runtime.h>
#include <hip/hip_fp16.h>

#define N_NODES 50000
#define N_EDGES 800000
#define D 64
#define NUM_GRAPHS 512
#define FINAL_NEURON 128
#define SCAN_NB ((N_NODES + 255) / 256)   // 196 blocks

typedef unsigned long long u64;

// ---------------- CSR build ----------------
__global__ void k_zero2(int* a, int* b, int n) {
    int i = blockIdx.x * blockDim.x + threadIdx.x;
    if (i < n) { a[i] = 0; b[i] = 0; }
}

__global__ void k_hist(const int* __restrict__ dst, int* cnt) {
    int e = blockIdx.x * blockDim.x + threadIdx.x;
    if (e < N_EDGES) atomicAdd(&cnt[dst[e]], 1);
}

// block sums of cnt; emit dinv = rsqrt(deg), sdeg = sqrt(deg); zero g
__global__ void k_blocksum(const int* __restrict__ cnt, int* __restrict__ bsum,
                           float* __restrict__ dinv, float* __restrict__ sdeg,
                           float* __restrict__ g) {
    __shared__ int sdata[256];
    int t = threadIdx.x;
    int i = blockIdx.x * 256 + t;
    int v = (i < N_NODES) ? cnt[i] : 0;
    if (i < N_NODES) {
        float deg = (float)v + 1.0f;
        dinv[i] = rsqrtf(deg);
        sdeg[i] = sqrtf(deg);
    }
    if (i < NUM_GRAPHS * D) g[i] = 0.f;
    sdata[t] = v;
    __syncthreads();
    for (int s = 128; s > 0; s >>= 1) {
        if (t < s) sdata[t] += sdata[t + s];
        __syncthreads();
    }
    if (t == 0) bsum[blockIdx.x] = sdata[0];
}

__global__ void k_scanbsum(const int* __restrict__ bsum, int* __restrict__ boff) {
    __shared__ int buf[256];
    int t = threadIdx.x;
    int v = (t < SCAN_NB) ? bsum[t] : 0;
    buf[t] = v;
    __syncthreads();
    for (int off = 1; off < 256; off <<= 1) {
        int a = (t >= off) ? buf[t - off] : 0;
        __syncthreads();
        buf[t] += a;
        __syncthreads();
    }
    if (t < SCAN_NB) boff[t] = buf[t] - v;   // exclusive
}

__global__ void k_localscan(const int* __restrict__ cnt, const int* __restrict__ boff,
                            int* __restrict__ row) {
    __shared__ int buf[256];
    int t = threadIdx.x;
    int i = blockIdx.x * 256 + t;
    int v = (i < N_NODES) ? cnt[i] : 0;
    buf[t] = v;
    __syncthreads();
    for (int off = 1; off < 256; off <<= 1) {
        int a = (t >= off) ? buf[t - off] : 0;
        __syncthreads();
        buf[t] += a;
        __syncthreads();
    }
    if (i < N_NODES) row[i] = boff[blockIdx.x] + buf[t] - v;
    if (i == 0) row[N_NODES] = N_EDGES;
}

// place each edge: ONE 4B store (src only; norm is folded into stored h).
#define FILL_GROUP_BLOCKS 392
__global__ void k_fill(const int* __restrict__ src, const int* __restrict__ dst,
                       const int* __restrict__ row, int* cur,
                       int* __restrict__ esrc) {
    int rng = blockIdx.x & 7;
    int lo = rng * (N_NODES / 8);
    int hi = (rng == 7) ? N_NODES : lo + (N_NODES / 8);
    int stride = FILL_GROUP_BLOCKS * 256;
    for (int e = (blockIdx.x >> 3) * 256 + threadIdx.x; e < N_EDGES; e += stride) {
        int d = dst[e];
        if (d < lo || d >= hi) continue;
        int pos = atomicAdd(&cur[d], 1);
        esrc[row[d] + pos] = src[e];
    }
}

// ---------------- x -> x_hat = dinv * x (fp16) ----------------
__global__ void k_tohalf(const float* __restrict__ x, const float* __restrict__ dinv,
                         __half* __restrict__ xh) {
    int i = blockIdx.x * blockDim.x + threadIdx.x;   // half2 index
    if (i < N_NODES * D / 2) {
        float2 f = ((const float2*)x)[i];
        float s = dinv[i >> 5];                      // node = (2i)/64
        ((__half2*)xh)[i] = __floats2half2_rn(f.x * s, f.y * s);
    }
}

// ---------------- fused GCN layer ----------------
// ĥ_in = dinv*h_in (fp16). agg[d] = dinv[d]*(Σ_{s in N(d)} ĥ[s] + ĥ[d]).
// Two feature phases (0-31, 32-63): per-phase gather working set = 3.2 MB
// < 4 MB per-XCD L2. 8 lanes/node, uint2 (4 halves) per lane per edge ->
// one 64B line per edge per phase. Edge stream nontemporal (no L2 pollution).
// Then mini-gemm vs W, bias+relu, re-scale by dinv[n], nt-store fp16.
__device__ __forceinline__ void acc_add(float4& a, uint2 u) {
    float2 p0 = __half22float2(*(const __half2*)&u.x);
    float2 p1 = __half22float2(*(const __half2*)&u.y);
    a.x += p0.x; a.y += p0.y; a.z += p1.x; a.w += p1.y;
}

__global__ __launch_bounds__(256, 6)
void k_layer(const int* __restrict__ row, const int* __restrict__ esrc,
             const __half* __restrict__ hin, const float* __restrict__ dinv,
             const float* __restrict__ W, const float* __restrict__ bias,
             __half* __restrict__ hout) {
    __shared__ float4 Ws4[D * 16];       // 16 KB
    __shared__ float  hs[32 * 68];       // 8.7 KB
    int t = threadIdx.x;
    int base = blockIdx.x * 32;

    const float4* W4 = (const float4*)W;
    for (int idx = t; idx < D * 16; idx += 256) Ws4[idx] = W4[idx];

    int c8 = t & 7;                      // 4-feature group within phase
    int ln = t >> 3;                     // local node 0..31
    int n = base + ln;
    const uint2* h2 = (const uint2*)hin; // row = 16 uint2 (128 B)

    if (n < N_NODES) {
        int e0 = row[n], e1 = row[n + 1];
        float sc = dinv[n];
        #pragma unroll
        for (int p = 0; p < 2; ++p) {
            size_t off = (size_t)(p * 8 + c8);
            float4 acc = {0.f, 0.f, 0.f, 0.f};
            int e = e0;
            for (; e + 4 <= e1; e += 4) {
                int s0 = __builtin_nontemporal_load(esrc + e);
                int s1 = __builtin_nontemporal_load(esrc + e + 1);
                int s2 = __builtin_nontemporal_load(esrc + e + 2);
                int s3 = __builtin_nontemporal_load(esrc + e + 3);
                uint2 u0 = h2[(size_t)s0 * 16 + off];
                uint2 u1 = h2[(size_t)s1 * 16 + off];
                uint2 u2 = h2[(size_t)s2 * 16 + off];
                uint2 u3 = h2[(size_t)s3 * 16 + off];
                acc_add(acc, u0); acc_add(acc, u1);
                acc_add(acc, u2); acc_add(acc, u3);
            }
            for (; e < e1; ++e) {
                int s = __builtin_nontemporal_load(esrc + e);
                acc_add(acc, h2[(size_t)s * 16 + off]);
            }
            acc_add(acc, h2[(size_t)n * 16 + off]);   // self-loop
            acc.x *= sc; acc.y *= sc; acc.z *= sc; acc.w *= sc;
            *(float4*)&hs[ln * 68 + p * 32 + c8 * 4] = acc;
        }
    } else {
        *(float4*)&hs[ln * 68 + c8 * 4]      = make_float4(0.f, 0.f, 0.f, 0.f);
        *(float4*)&hs[ln * 68 + 32 + c8 * 4] = make_float4(0.f, 0.f, 0.f, 0.f);
    }
    __syncthreads();

    // mini-gemm: rows rt, rt+1; cols c*4..c*4+3
    int c = t & 15;
    int rt = (t >> 4) * 2;
    float4 acc0 = {0,0,0,0}, acc1 = {0,0,0,0};
    #pragma unroll 4
    for (int k = 0; k < D; ++k) {
        float a0 = hs[(rt + 0) * 68 + k];
        float a1 = hs[(rt + 1) * 68 + k];
        float4 w = Ws4[k * 16 + c];
        acc0.x += a0 * w.x; acc0.y += a0 * w.y; acc0.z += a0 * w.z; acc0.w += a0 * w.w;
        acc1.x += a1 * w.x; acc1.y += a1 * w.y; acc1.z += a1 * w.z; acc1.w += a1 * w.w;
    }
    float4 bb = ((const float4*)bias)[c];
    int n0 = base + rt, n1 = base + rt + 1;
    if (n0 < N_NODES) {
        float s0 = dinv[n0];
        __half2 lo = __floats2half2_rn(fmaxf(acc0.x + bb.x, 0.f) * s0,
                                       fmaxf(acc0.y + bb.y, 0.f) * s0);
        __half2 hi = __floats2half2_rn(fmaxf(acc0.z + bb.z, 0.f) * s0,
                                       fmaxf(acc0.w + bb.w, 0.f) * s0);
        u64 pk = (u64)(*(unsigned*)&lo) | ((u64)(*(unsigned*)&hi) << 32);
        __builtin_nontemporal_store(pk, (u64*)hout + (size_t)n0 * 16 + c);
    }
    if (n1 < N_NODES) {
        float s1 = dinv[n1];
        __half2 lo = __floats2half2_rn(fmaxf(acc1.x + bb.x, 0.f) * s1,
                                       fmaxf(acc1.y + bb.y, 0.f) * s1);
        __half2 hi = __floats2half2_rn(fmaxf(acc1.z + bb.z, 0.f) * s1,
                                       fmaxf(acc1.w + bb.w, 0.f) * s1);
        u64 pk = (u64)(*(unsigned*)&lo) | ((u64)(*(unsigned*)&hi) << 32);
        __builtin_nontemporal_store(pk, (u64*)hout + (size_t)n1 * 16 + c);
    }
}

// ---------------- pooling: g += sdeg[n] * ĥ5[n] (un-scales dinv) ----------------
__global__ void k_pool(const int* __restrict__ batch, const __half* __restrict__ h,
                       const float* __restrict__ sdeg, float* g) {
    int tid = blockIdx.x * blockDim.x + threadIdx.x;
    int f = tid & 63;
    int n0 = (tid >> 6) * 8;
    if (n0 >= N_NODES) return;
    int n1 = n0 + 8; if (n1 > N_NODES) n1 = N_NODES;
    int curb = batch[n0];
    float acc = 0.f;
    for (int n = n0; n < n1; ++n) {
        int bb = batch[n];
        if (bb != curb) { atomicAdd(&g[curb * D + f], acc); acc = 0.f; curb = bb; }
        acc += __half2float(h[(size_t)n * D + f]) * sdeg[n];
    }
    atomicAdd(&g[curb * D + f], acc);
}

// ---------------- fused MLP ----------------
__global__ void k_mlp(const float* __restrict__ g, const float* __restrict__ W1,
                      const float* __restrict__ b1, const float* __restrict__ W2,
                      const float* __restrict__ b2, float* __restrict__ out) {
    __shared__ float red[FINAL_NEURON];
    int row = blockIdx.x;
    int j = threadIdx.x;
    float acc = 0.f;
    #pragma unroll
    for (int k = 0; k < D; ++k) acc += g[row * D + k] * W1[k * FINAL_NEURON + j];
    acc = fmaxf(acc + b1[j], 0.f);
    red[j] = acc * W2[j];
    __syncthreads();
    for (int s = 64; s > 0; s >>= 1) {
        if (j < s) red[j] += red[j + s];
        __syncthreads();
    }
    if (j == 0) out[row] = red[0] + b2[0];
}

extern "C" void kernel_launch(void* const* d_in, const int* in_sizes, int n_in,
                              void* d_out, int out_size, void* d_ws, size_t ws_size,
                              hipStream_t stream) {
    const float* x     = (const float*)d_in[0];
    const int*   ei    = (const int*)d_in[1];
    const int*   src   = ei;
    const int*   dst   = ei + N_EDGES;
    const int*   batch = (const int*)d_in[2];
    const float* W[5]  = {(const float*)d_in[3], (const float*)d_in[5], (const float*)d_in[7],
                          (const float*)d_in[9], (const float*)d_in[11]};
    const float* b[5]  = {(const float*)d_in[4], (const float*)d_in[6], (const float*)d_in[8],
                          (const float*)d_in[10], (const float*)d_in[12]};
    const float* fc1W  = (const float*)d_in[13];
    const float* fc1b  = (const float*)d_in[14];
    const float* fc2W  = (const float*)d_in[15];
    const float* fc2b  = (const float*)d_in[16];
    float* out = (float*)d_out;

    // ws layout: 16B-aligned vector arrays first, ints last.
    int*    esrc = (int*)d_ws;                         // E int (3.2 MB)
    __half* xh   = (__half*)(esrc + N_EDGES);          // N*D half
    __half* hA   = xh + (size_t)N_NODES * D;           // N*D half
    __half* hB   = hA + (size_t)N_NODES * D;           // N*D half
    float*  g    = (float*)(hB + (size_t)N_NODES * D); // G*D
    float*  dinv = g + NUM_GRAPHS * D;                 // N
    float*  sdeg = dinv + N_NODES;                     // N
    int*    cnt  = (int*)(sdeg + N_NODES);             // N
    int*    row  = cnt + N_NODES;                      // N+1
    int*    cur  = row + N_NODES + 1;                  // N
    int*    bsum = cur + N_NODES;                      // 256
    int*    boff = bsum + 256;                         // 256

    // ---- CSR build + x scaling ----
    k_zero2<<<(N_NODES + 255) / 256, 256, 0, stream>>>(cnt, cur, N_NODES);
    k_hist<<<(N_EDGES + 255) / 256, 256, 0, stream>>>(dst, cnt);
    k_blocksum<<<SCAN_NB, 256, 0, stream>>>(cnt, bsum, dinv, sdeg, g);
    k_tohalf<<<(N_NODES * D / 2 + 255) / 256, 256, 0, stream>>>(x, dinv, xh);
    k_scanbsum<<<1, 256, 0, stream>>>(bsum, boff);
    k_localscan<<<SCAN_NB, 256, 0, stream>>>(cnt, boff, row);
    k_fill<<<FILL_GROUP_BLOCKS * 8, 256, 0, stream>>>(src, dst, row, cur, esrc);

    // ---- 5 fused GCN layers (ping-pong) ----
    const int NB = (N_NODES + 31) / 32;
    k_layer<<<NB, 256, 0, stream>>>(row, esrc, xh, dinv, W[0], b[0], hA);
    k_layer<<<NB, 256, 0, stream>>>(row, esrc, hA, dinv, W[1], b[1], hB);
    k_layer<<<NB, 256, 0, stream>>>(row, esrc, hB, dinv, W[2], b[2], hA);
    k_layer<<<NB, 256, 0, stream>>>(row, esrc, hA, dinv, W[3], b[3], hB);
    k_layer<<<NB, 256, 0, stream>>>(row, esrc, hB, dinv, W[4], b[4], hA);

    // ---- readout + fused MLP ----
    k_pool<<<((N_NODES + 7) / 8 * 64 + 255) / 256, 256, 0, stream>>>(batch, hA, sdeg, g);
    k_mlp<<<NUM_GRAPHS, FINAL_NEURON, 0, stream>>>(g, fc1W, fc1b, fc2W, fc2b, out);
}

// Round 11
// 315.015 us; speedup vs baseline: 1.2216x; 1.2216x over previous
//
#include <hip/hip_runtime.h>
#include <hip/hip_fp16.h>

#define N_NODES 50000
#define N_EDGES 800000
#define D 64
#define NUM_GRAPHS 512
#define FINAL_NEURON 128
#define SCAN_NB ((N_NODES + 255) / 256)   // 196 blocks

typedef unsigned long long u64;

// ---------------- CSR build ----------------
__global__ void k_zero2(int* a, int* b, int n) {
    int i = blockIdx.x * blockDim.x + threadIdx.x;
    if (i < n) { a[i] = 0; b[i] = 0; }
}

__global__ void k_hist(const int* __restrict__ dst, int* cnt) {
    int e = blockIdx.x * blockDim.x + threadIdx.x;
    if (e < N_EDGES) atomicAdd(&cnt[dst[e]], 1);
}

// block sums of cnt; emit dinv = rsqrt(deg), sdeg = sqrt(deg); zero g
__global__ void k_blocksum(const int* __restrict__ cnt, int* __restrict__ bsum,
                           float* __restrict__ dinv, float* __restrict__ sdeg,
                           float* __restrict__ g) {
    __shared__ int sdata[256];
    int t = threadIdx.x;
    int i = blockIdx.x * 256 + t;
    int v = (i < N_NODES) ? cnt[i] : 0;
    if (i < N_NODES) {
        float deg = (float)v + 1.0f;
        dinv[i] = rsqrtf(deg);
        sdeg[i] = sqrtf(deg);
    }
    if (i < NUM_GRAPHS * D) g[i] = 0.f;
    sdata[t] = v;
    __syncthreads();
    for (int s = 128; s > 0; s >>= 1) {
        if (t < s) sdata[t] += sdata[t + s];
        __syncthreads();
    }
    if (t == 0) bsum[blockIdx.x] = sdata[0];
}

__global__ void k_scanbsum(const int* __restrict__ bsum, int* __restrict__ boff) {
    __shared__ int buf[256];
    int t = threadIdx.x;
    int v = (t < SCAN_NB) ? bsum[t] : 0;
    buf[t] = v;
    __syncthreads();
    for (int off = 1; off < 256; off <<= 1) {
        int a = (t >= off) ? buf[t - off] : 0;
        __syncthreads();
        buf[t] += a;
        __syncthreads();
    }
    if (t < SCAN_NB) boff[t] = buf[t] - v;   // exclusive
}

__global__ void k_localscan(const int* __restrict__ cnt, const int* __restrict__ boff,
                            int* __restrict__ row) {
    __shared__ int buf[256];
    int t = threadIdx.x;
    int i = blockIdx.x * 256 + t;
    int v = (i < N_NODES) ? cnt[i] : 0;
    buf[t] = v;
    __syncthreads();
    for (int off = 1; off < 256; off <<= 1) {
        int a = (t >= off) ? buf[t - off] : 0;
        __syncthreads();
        buf[t] += a;
        __syncthreads();
    }
    if (i < N_NODES) row[i] = boff[blockIdx.x] + buf[t] - v;
    if (i == 0) row[N_NODES] = N_EDGES;
}

// place each edge: ONE 4B store (src only; norm folded into stored h).
#define FILL_GROUP_BLOCKS 392
__global__ void k_fill(const int* __restrict__ src, const int* __restrict__ dst,
                       const int* __restrict__ row, int* cur,
                       int* __restrict__ esrc) {
    int rng = blockIdx.x & 7;
    int lo = rng * (N_NODES / 8);
    int hi = (rng == 7) ? N_NODES : lo + (N_NODES / 8);
    int stride = FILL_GROUP_BLOCKS * 256;
    for (int e = (blockIdx.x >> 3) * 256 + threadIdx.x; e < N_EDGES; e += stride) {
        int d = dst[e];
        if (d < lo || d >= hi) continue;
        int pos = atomicAdd(&cur[d], 1);
        esrc[row[d] + pos] = src[e];
    }
}

// ---------------- x -> x_hat = dinv * x (fp16) ----------------
__global__ void k_tohalf(const float* __restrict__ x, const float* __restrict__ dinv,
                         __half* __restrict__ xh) {
    int i = blockIdx.x * blockDim.x + threadIdx.x;   // half2 index
    if (i < N_NODES * D / 2) {
        float2 f = ((const float2*)x)[i];
        float s = dinv[i >> 5];                      // node = (2i)/64
        ((__half2*)xh)[i] = __floats2half2_rn(f.x * s, f.y * s);
    }
}

// ---------------- fused GCN layer ----------------
// ĥ_in = dinv*h_in (fp16). agg[d] = dinv[d]*(Σ_{s∈N(d)} ĥ[s] + ĥ[d]).
// Single-phase gather (R9 structure): 8 lanes/node, each lane one uint4
// (8 halves, 16B); edge stream is 4B/edge, pure adds (norm pre-folded).
// Then mini-gemm vs W (float4 LDS reads), bias+relu, re-scale, fp16 store.
__device__ __forceinline__ void acc_add8(float4& a0, float4& a1, uint4 u) {
    float2 p;
    p = __half22float2(*(const __half2*)&u.x); a0.x += p.x; a0.y += p.y;
    p = __half22float2(*(const __half2*)&u.y); a0.z += p.x; a0.w += p.y;
    p = __half22float2(*(const __half2*)&u.z); a1.x += p.x; a1.y += p.y;
    p = __half22float2(*(const __half2*)&u.w); a1.z += p.x; a1.w += p.y;
}

__global__ __launch_bounds__(256, 6)
void k_layer(const int* __restrict__ row, const int* __restrict__ esrc,
             const __half* __restrict__ hin, const float* __restrict__ dinv,
             const float* __restrict__ W, const float* __restrict__ bias,
             __half* __restrict__ hout) {
    __shared__ float4 Ws4[D * 16];       // 16 KB
    __shared__ float  hs[32 * 68];       // 8.7 KB
    int t = threadIdx.x;
    int base = blockIdx.x * 32;

    const float4* W4 = (const float4*)W;
    for (int idx = t; idx < D * 16; idx += 256) Ws4[idx] = W4[idx];

    // ---- phase 1: gather ----
    {
        int c8 = t & 7;                  // 8-feature group
        int ln = t >> 3;                 // local node 0..31
        int n = base + ln;
        const uint4* h16 = (const uint4*)hin;   // row = 8 x uint4
        float4 a0 = {0,0,0,0}, a1 = {0,0,0,0};
        if (n < N_NODES) {
            int e = row[n], e1 = row[n + 1];
            for (; e + 4 <= e1; e += 4) {
                int s0 = esrc[e], s1 = esrc[e + 1], s2 = esrc[e + 2], s3 = esrc[e + 3];
                uint4 u0 = h16[(size_t)s0 * 8 + c8];
                uint4 u1 = h16[(size_t)s1 * 8 + c8];
                uint4 u2 = h16[(size_t)s2 * 8 + c8];
                uint4 u3 = h16[(size_t)s3 * 8 + c8];
                acc_add8(a0, a1, u0); acc_add8(a0, a1, u1);
                acc_add8(a0, a1, u2); acc_add8(a0, a1, u3);
            }
            for (; e < e1; ++e)
                acc_add8(a0, a1, h16[(size_t)esrc[e] * 8 + c8]);
            acc_add8(a0, a1, h16[(size_t)n * 8 + c8]);   // self-loop
            float sc = dinv[n];
            a0.x *= sc; a0.y *= sc; a0.z *= sc; a0.w *= sc;
            a1.x *= sc; a1.y *= sc; a1.z *= sc; a1.w *= sc;
        }
        *(float4*)&hs[ln * 68 + c8 * 8]     = a0;
        *(float4*)&hs[ln * 68 + c8 * 8 + 4] = a1;
    }
    __syncthreads();

    // ---- phase 2: mini-gemm, rows rt, rt+1; cols c*4..c*4+3 ----
    int c = t & 15;
    int rt = (t >> 4) * 2;
    float4 acc0 = {0,0,0,0}, acc1 = {0,0,0,0};
    #pragma unroll 2
    for (int kk = 0; kk < 16; ++kk) {
        float4 h0 = *(const float4*)&hs[(rt + 0) * 68 + kk * 4];
        float4 h1 = *(const float4*)&hs[(rt + 1) * 68 + kk * 4];
        float4 w0 = Ws4[(kk * 4 + 0) * 16 + c];
        float4 w1 = Ws4[(kk * 4 + 1) * 16 + c];
        float4 w2 = Ws4[(kk * 4 + 2) * 16 + c];
        float4 w3 = Ws4[(kk * 4 + 3) * 16 + c];
        acc0.x += h0.x * w0.x + h0.y * w1.x + h0.z * w2.x + h0.w * w3.x;
        acc0.y += h0.x * w0.y + h0.y * w1.y + h0.z * w2.y + h0.w * w3.y;
        acc0.z += h0.x * w0.z + h0.y * w1.z + h0.z * w2.z + h0.w * w3.z;
        acc0.w += h0.x * w0.w + h0.y * w1.w + h0.z * w2.w + h0.w * w3.w;
        acc1.x += h1.x * w0.x + h1.y * w1.x + h1.z * w2.x + h1.w * w3.x;
        acc1.y += h1.x * w0.y + h1.y * w1.y + h1.z * w2.y + h1.w * w3.y;
        acc1.z += h1.x * w0.z + h1.y * w1.z + h1.z * w2.z + h1.w * w3.z;
        acc1.w += h1.x * w0.w + h1.y * w1.w + h1.z * w2.w + h1.w * w3.w;
    }
    float4 bb = ((const float4*)bias)[c];
    int n0 = base + rt, n1 = base + rt + 1;
    if (n0 < N_NODES) {
        float s0 = dinv[n0];
        __half2 lo = __floats2half2_rn(fmaxf(acc0.x + bb.x, 0.f) * s0,
                                       fmaxf(acc0.y + bb.y, 0.f) * s0);
        __half2 hi = __floats2half2_rn(fmaxf(acc0.z + bb.z, 0.f) * s0,
                                       fmaxf(acc0.w + bb.w, 0.f) * s0);
        uint2 pk = {*(unsigned*)&lo, *(unsigned*)&hi};
        ((uint2*)hout)[(size_t)n0 * 16 + c] = pk;
    }
    if (n1 < N_NODES) {
        float s1 = dinv[n1];
        __half2 lo = __floats2half2_rn(fmaxf(acc1.x + bb.x, 0.f) * s1,
                                       fmaxf(acc1.y + bb.y, 0.f) * s1);
        __half2 hi = __floats2half2_rn(fmaxf(acc1.z + bb.z, 0.f) * s1,
                                       fmaxf(acc1.w + bb.w, 0.f) * s1);
        uint2 pk = {*(unsigned*)&lo, *(unsigned*)&hi};
        ((uint2*)hout)[(size_t)n1 * 16 + c] = pk;
    }
}

// ---------------- pooling: g += sdeg[n] * ĥ5[n] (un-scales dinv) ----------------
__global__ void k_pool(const int* __restrict__ batch, const __half* __restrict__ h,
                       const float* __restrict__ sdeg, float* g) {
    int tid = blockIdx.x * blockDim.x + threadIdx.x;
    int f = tid & 63;
    int n0 = (tid >> 6) * 8;
    if (n0 >= N_NODES) return;
    int n1 = n0 + 8; if (n1 > N_NODES) n1 = N_NODES;
    int curb = batch[n0];
    float acc = 0.f;
    for (int n = n0; n < n1; ++n) {
        int bb = batch[n];
        if (bb != curb) { atomicAdd(&g[curb * D + f], acc); acc = 0.f; curb = bb; }
        acc += __half2float(h[(size_t)n * D + f]) * sdeg[n];
    }
    atomicAdd(&g[curb * D + f], acc);
}

// ---------------- fused MLP ----------------
__global__ void k_mlp(const float* __restrict__ g, const float* __restrict__ W1,
                      const float* __restrict__ b1, const float* __restrict__ W2,
                      const float* __restrict__ b2, float* __restrict__ out) {
    __shared__ float red[FINAL_NEURON];
    int row = blockIdx.x;
    int j = threadIdx.x;
    float acc = 0.f;
    #pragma unroll
    for (int k = 0; k < D; ++k) acc += g[row * D + k] * W1[k * FINAL_NEURON + j];
    acc = fmaxf(acc + b1[j], 0.f);
    red[j] = acc * W2[j];
    __syncthreads();
    for (int s = 64; s > 0; s >>= 1) {
        if (j < s) red[j] += red[j + s];
        __syncthreads();
    }
    if (j == 0) out[row] = red[0] + b2[0];
}

extern "C" void kernel_launch(void* const* d_in, const int* in_sizes, int n_in,
                              void* d_out, int out_size, void* d_ws, size_t ws_size,
                              hipStream_t stream) {
    const float* x     = (const float*)d_in[0];
    const int*   ei    = (const int*)d_in[1];
    const int*   src   = ei;
    const int*   dst   = ei + N_EDGES;
    const int*   batch = (const int*)d_in[2];
    const float* W[5]  = {(const float*)d_in[3], (const float*)d_in[5], (const float*)d_in[7],
                          (const float*)d_in[9], (const float*)d_in[11]};
    const float* b[5]  = {(const float*)d_in[4], (const float*)d_in[6], (const float*)d_in[8],
                          (const float*)d_in[10], (const float*)d_in[12]};
    const float* fc1W  = (const float*)d_in[13];
    const float* fc1b  = (const float*)d_in[14];
    const float* fc2W  = (const float*)d_in[15];
    const float* fc2b  = (const float*)d_in[16];
    float* out = (float*)d_out;

    // ws layout: 16B-aligned vector arrays first, ints last.
    int*    esrc = (int*)d_ws;                         // E int (3.2 MB)
    __half* xh   = (__half*)(esrc + N_EDGES);          // N*D half
    __half* hA   = xh + (size_t)N_NODES * D;           // N*D half
    __half* hB   = hA + (size_t)N_NODES * D;           // N*D half
    float*  g    = (float*)(hB + (size_t)N_NODES * D); // G*D
    float*  dinv = g + NUM_GRAPHS * D;                 // N
    float*  sdeg = dinv + N_NODES;                     // N
    int*    cnt  = (int*)(sdeg + N_NODES);             // N
    int*    row  = cnt + N_NODES;                      // N+1
    int*    cur  = row + N_NODES + 1;                  // N
    int*    bsum = cur + N_NODES;                      // 256
    int*    boff = bsum + 256;                         // 256

    // ---- CSR build + x scaling ----
    k_zero2<<<(N_NODES + 255) / 256, 256, 0, stream>>>(cnt, cur, N_NODES);
    k_hist<<<(N_EDGES + 255) / 256, 256, 0, stream>>>(dst, cnt);
    k_blocksum<<<SCAN_NB, 256, 0, stream>>>(cnt, bsum, dinv, sdeg, g);
    k_tohalf<<<(N_NODES * D / 2 + 255) / 256, 256, 0, stream>>>(x, dinv, xh);
    k_scanbsum<<<1, 256, 0, stream>>>(bsum, boff);
    k_localscan<<<SCAN_NB, 256, 0, stream>>>(cnt, boff, row);
    k_fill<<<FILL_GROUP_BLOCKS * 8, 256, 0, stream>>>(src, dst, row, cur, esrc);

    // ---- 5 fused GCN layers (ping-pong) ----
    const int NB = (N_NODES + 31) / 32;
    k_layer<<<NB, 256, 0, stream>>>(row, esrc, xh, dinv, W[0], b[0], hA);
    k_layer<<<NB, 256, 0, stream>>>(row, esrc, hA, dinv, W[1], b[1], hB);
    k_layer<<<NB, 256, 0, stream>>>(row, esrc, hB, dinv, W[2], b[2], hA);
    k_layer<<<NB, 256, 0, stream>>>(row, esrc, hA, dinv, W[3], b[3], hB);
    k_layer<<<NB, 256, 0, stream>>>(row, esrc, hB, dinv, W[4], b[4], hA);

    // ---- readout + fused MLP ----
    k_pool<<<((N_NODES + 7) / 8 * 64 + 255) / 256, 256, 0, stream>>>(batch, hA, sdeg, g);
    k_mlp<<<NUM_GRAPHS, FINAL_NEURON, 0, stream>>>(g, fc1W, fc1b, fc2W, fc2b, out);
}